// Round 6
// baseline (147.311 us; speedup 1.0000x reference)
//
#include <hip/hip_runtime.h>
#include <math.h>

#define NPIX 50176      // 16*56*56
#define CDIM 384
#define HEADS 6
#define NLOGIT 54       // HEADS*9
#define HH 56
#define WW 56

typedef __attribute__((ext_vector_type(8))) __bf16 bf16x8;
typedef __attribute__((ext_vector_type(4))) float f32x4;

__device__ __forceinline__ void glds16(const void* g, void* l) {
  __builtin_amdgcn_global_load_lds(
      (const __attribute__((address_space(1))) unsigned int*)g,
      (__attribute__((address_space(3))) unsigned int*)l, 16, 0, 0);
}

// ---------------------------------------------------------------------------
// W_attn [384][54] fp32 -> Wfrag bf16, MFMA-B-fragment-major:
// element (ks*2048 + ni*512 + lane*8 + q) = W[k=ks*32+(lane>>4)*8+q]
//                                            [n=ni*16+(lane&15)]
// (zero for n >= 54). Also bpad[64].
// ---------------------------------------------------------------------------
__global__ __launch_bounds__(256) void pad_attn_frag_kernel(
    const float* __restrict__ W, const float* __restrict__ b,
    __bf16* __restrict__ Wfrag, float* __restrict__ bpad) {
  const int gid = blockIdx.x * 256 + threadIdx.x;  // 0..3071
  if (gid < 3072) {
    const int ks   = gid >> 8;
    const int rem  = gid & 255;
    const int ni   = rem >> 6;
    const int lane = rem & 63;
    const int n = ni * 16 + (lane & 15);
    const int k = ks * 32 + (lane >> 4) * 8;
    bf16x8 o;
    #pragma unroll
    for (int q = 0; q < 8; ++q)
      o[q] = (__bf16)((n < NLOGIT) ? W[(k + q) * NLOGIT + n] : 0.f);
    *(bf16x8*)&Wfrag[gid * 8] = o;
  }
  if (gid < 64) bpad[gid] = (gid < NLOGIT) ? b[gid] : 0.f;
}

// ---------------------------------------------------------------------------
// Cast + transpose weight: W fp32 [K][N] (384x384) -> Wt bf16 [N][K].
// ---------------------------------------------------------------------------
__global__ __launch_bounds__(256) void cast_wt_kernel(
    const float* __restrict__ W, __bf16* __restrict__ Wt) {
  const int idx = blockIdx.x * 256 + threadIdx.x;  // 384*384 = 147456
  const int n = idx / CDIM, k = idx % CDIM;
  Wt[n * CDIM + k] = (__bf16)W[k * CDIM + n];
}

// ---------------------------------------------------------------------------
// Cast x fp32 -> bf16, 16 elements / thread. Pure streaming.
// ---------------------------------------------------------------------------
__global__ __launch_bounds__(256) void cast_x_kernel(
    const float* __restrict__ x, __bf16* __restrict__ xb) {
  const size_t i = (size_t)blockIdx.x * 256 + threadIdx.x;  // 1204224 threads
  const float4* src = (const float4*)x + i * 4;
  const float4 f0 = src[0];
  const float4 f1 = src[1];
  const float4 f2 = src[2];
  const float4 f3 = src[3];
  bf16x8 o0, o1;
  o0[0] = (__bf16)f0.x; o0[1] = (__bf16)f0.y; o0[2] = (__bf16)f0.z; o0[3] = (__bf16)f0.w;
  o0[4] = (__bf16)f1.x; o0[5] = (__bf16)f1.y; o0[6] = (__bf16)f1.z; o0[7] = (__bf16)f1.w;
  o1[0] = (__bf16)f2.x; o1[1] = (__bf16)f2.y; o1[2] = (__bf16)f2.z; o1[3] = (__bf16)f2.w;
  o1[4] = (__bf16)f3.x; o1[5] = (__bf16)f3.y; o1[6] = (__bf16)f3.z; o1[7] = (__bf16)f3.w;
  ((bf16x8*)xb)[i * 2]     = o0;
  ((bf16x8*)xb)[i * 2 + 1] = o1;
}

// ---------------------------------------------------------------------------
// Logits via bf16 MFMA, reading pre-cast xb. BM=64, 4 waves; wave w owns
// rows [bm+w*16, +16), all 64 cols (acc[4]). Weight LDS-resident in
// fragment order. K-loop: 1 bf16x8 global load + 4 ds_read + 4 MFMA.
// ---------------------------------------------------------------------------
__global__ __launch_bounds__(256) void logit_softmax_kernel(
    const __bf16* __restrict__ xb, const __bf16* __restrict__ Wfrag,
    const float* __restrict__ bpad, float* __restrict__ attn) {
  __shared__ char smem[49152];                 // 48KB: Wl, then reused as Ls
  __bf16* Wl = (__bf16*)smem;
  float (*Ls)[68] = (float(*)[68])smem;        // 64x68 f32 = 17408B

  const int tid  = threadIdx.x;
  const int wave = tid >> 6;
  const int lane = tid & 63;
  const int bm   = blockIdx.x * 64;
  const int frow = lane & 15;
  const int fk   = (lane >> 4) * 8;

  // stage whole weight: 48KB = 12 x (256 threads x 16B), contiguous
  #pragma unroll
  for (int i = 0; i < 12; ++i) {
    const int off = (i * 256 + tid) * 8;       // bf16 elements
    glds16(Wfrag + off, Wl + off);
  }
  __syncthreads();

  f32x4 acc[4] = {};
  const int arow = bm + wave * 16 + frow;
  const __bf16* gx = xb + (size_t)arow * CDIM + fk;

  #pragma unroll
  for (int ks = 0; ks < 12; ++ks) {
    const bf16x8 a = *(const bf16x8*)(gx + ks * 32);
    #pragma unroll
    for (int ni = 0; ni < 4; ++ni) {
      const bf16x8 bfr = *(const bf16x8*)&Wl[ks * 2048 + ni * 512 + lane * 8];
      acc[ni] = __builtin_amdgcn_mfma_f32_16x16x32_bf16(
          a, bfr, acc[ni], 0, 0, 0);
    }
  }

  __syncthreads();  // all waves done with Wl before overwriting with Ls

  float bvl[4];
  #pragma unroll
  for (int ni = 0; ni < 4; ++ni) bvl[ni] = bpad[ni * 16 + frow];
  const int orow = (lane >> 4) * 4;
  #pragma unroll
  for (int ni = 0; ni < 4; ++ni)
    #pragma unroll
    for (int r = 0; r < 4; ++r)
      Ls[wave * 16 + orow + r][ni * 16 + frow] = acc[ni][r] + bvl[ni];
  __syncthreads();

  // 64 pixels * 6 heads = 384 softmax tasks over 256 threads
  #pragma unroll
  for (int it = 0; it < 2; ++it) {
    const int task = it * 256 + tid;
    if (task < 64 * HEADS) {
      const int pl = task / HEADS;
      const int h  = task % HEADS;
      const float* row = &Ls[pl][h * 9];
      float m = row[0];
      #pragma unroll
      for (int w = 1; w < 9; ++w) m = fmaxf(m, row[w]);
      float e[9], s = 0.f;
      #pragma unroll
      for (int w = 0; w < 9; ++w) { e[w] = __expf(row[w] - m); s += e[w]; }
      const float inv = 1.f / s;
      float* op = &attn[(size_t)(bm + pl) * NLOGIT + h * 9];
      #pragma unroll
      for (int w = 0; w < 9; ++w) op[w] = e[w] * inv;
    }
  }
}

// ---------------------------------------------------------------------------
// bf16 MFMA GEMM: Out[M][N] = A[M][K] @ Bt[N][K]^T + bias.
// 128x128 tile, BK=32, 256 threads (4 waves, 2x2 of 64x64 wave-tiles).
// ---------------------------------------------------------------------------
template <bool OUT_BF16>
__global__ __launch_bounds__(256) void gemm_bf16_kernel(
    const __bf16* __restrict__ A, const __bf16* __restrict__ Bt,
    const float* __restrict__ bias, void* __restrict__ Out,
    int M, int N, int Kd) {
  __shared__ __bf16 As[128][32];
  __shared__ __bf16 Bs[128][32];

  const int tid  = threadIdx.x;
  const int wave = tid >> 6;
  const int lane = tid & 63;
  const int bm = blockIdx.x * 128;
  const int bn = blockIdx.y * 128;

  const int lrow   = lane >> 2;
  const int lkoff  = (lane & 3) * 8;
  const int frow   = lane & 15;
  const int fk     = (lane >> 4) * 8;
  const int wr = (wave >> 1) * 64;
  const int wc = (wave & 1) * 64;

  f32x4 acc[4][4] = {};

  for (int k0 = 0; k0 < Kd; k0 += 32) {
    const __bf16* ga = A  + (size_t)(bm + wave * 32 + lrow) * Kd + k0 + lkoff;
    const __bf16* gb = Bt + (size_t)(bn + wave * 32 + lrow) * Kd + k0 + lkoff;
    glds16(ga,                    &As[wave * 32][0]);
    glds16(ga + 16 * (size_t)Kd,  &As[wave * 32 + 16][0]);
    glds16(gb,                    &Bs[wave * 32][0]);
    glds16(gb + 16 * (size_t)Kd,  &Bs[wave * 32 + 16][0]);
    __syncthreads();

    bf16x8 a[4], b[4];
    #pragma unroll
    for (int mi = 0; mi < 4; ++mi)
      a[mi] = *(const bf16x8*)&As[wr + mi * 16 + frow][fk];
    #pragma unroll
    for (int ni = 0; ni < 4; ++ni)
      b[ni] = *(const bf16x8*)&Bs[wc + ni * 16 + frow][fk];
    #pragma unroll
    for (int mi = 0; mi < 4; ++mi)
      #pragma unroll
      for (int ni = 0; ni < 4; ++ni)
        acc[mi][ni] = __builtin_amdgcn_mfma_f32_16x16x32_bf16(
            a[mi], b[ni], acc[mi][ni], 0, 0, 0);
    __syncthreads();
  }

  const int orow = (lane >> 4) * 4;
  const int ocol = lane & 15;
  #pragma unroll
  for (int mi = 0; mi < 4; ++mi) {
    #pragma unroll
    for (int ni = 0; ni < 4; ++ni) {
      const int n = bn + wc + ni * 16 + ocol;
      const float bvl = bias[n];
      #pragma unroll
      for (int r = 0; r < 4; ++r) {
        const int m = bm + wr + mi * 16 + orow + r;
        const float val = acc[mi][ni][r] + bvl;
        if (OUT_BF16)
          ((__bf16*)Out)[(size_t)m * N + n] = (__bf16)val;
        else
          ((float*)Out)[(size_t)m * N + n] = val;
      }
    }
  }
}

// ---------------------------------------------------------------------------
// Window aggregation on bf16 v: y[p,c] = sum_w attn[p,head(c),w]*v[nbr(p,w),c]
// ---------------------------------------------------------------------------
__global__ __launch_bounds__(256) void aggregate_kernel(
    const __bf16* __restrict__ v, const float* __restrict__ attn,
    __bf16* __restrict__ y) {
  const int idx = blockIdx.x * 256 + threadIdx.x;  // NPIX*48
  const int p  = idx / 48;
  const int cg = idx % 48;
  const int c  = cg * 8;
  const int b  = p / (HH * WW);
  const int ij = p % (HH * WW);
  const int i  = ij / WW;
  const int j  = ij % WW;
  const int head = c >> 6;

  const float* ap = attn + (size_t)p * NLOGIT + head * 9;
  float aw[9];
  #pragma unroll
  for (int w = 0; w < 9; ++w) aw[w] = ap[w];

  float acc[8] = {};
  #pragma unroll
  for (int ki = 0; ki < 3; ++ki) {
    const int ii = i + ki - 1;
    if (ii < 0 || ii >= HH) continue;
    #pragma unroll
    for (int kj = 0; kj < 3; ++kj) {
      const int jj = j + kj - 1;
      if (jj < 0 || jj >= WW) continue;
      const float w = aw[ki * 3 + kj];
      const bf16x8 vv =
          *(const bf16x8*)&v[((size_t)(b * HH + ii) * WW + jj) * CDIM + c];
      #pragma unroll
      for (int q = 0; q < 8; ++q) acc[q] += w * (float)vv[q];
    }
  }
  bf16x8 o;
  #pragma unroll
  for (int q = 0; q < 8; ++q) o[q] = (__bf16)acc[q];
  *(bf16x8*)&y[(size_t)p * CDIM + c] = o;
}

// ---------------------------------------------------------------------------
extern "C" void kernel_launch(void* const* d_in, const int* in_sizes, int n_in,
                              void* d_out, int out_size, void* d_ws,
                              size_t ws_size, hipStream_t stream) {
  const float* x      = (const float*)d_in[0];
  const float* W_attn = (const float*)d_in[1];
  const float* b_attn = (const float*)d_in[2];
  const float* W_v    = (const float*)d_in[3];
  const float* b_v    = (const float*)d_in[4];
  const float* W_proj = (const float*)d_in[5];
  const float* b_proj = (const float*)d_in[6];
  float* out = (float*)d_out;

  char* w = (char*)d_ws;
  __bf16* xb    = (__bf16*)w;  w += (size_t)NPIX * CDIM * 2;   // 38.5MB
  __bf16* v     = (__bf16*)w;  w += (size_t)NPIX * CDIM * 2;   // 38.5MB
  __bf16* y     = (__bf16*)w;  w += (size_t)NPIX * CDIM * 2;   // 38.5MB
  float*  attn  = (float*)w;   w += (size_t)NPIX * NLOGIT * 4; // 10.8MB
  __bf16* Wfrag = (__bf16*)w;  w += 64 * CDIM * 2;             // 48KB
  float*  bpad  = (float*)w;   w += 64 * 4;
  __bf16* Wtv   = (__bf16*)w;  w += CDIM * CDIM * 2;
  __bf16* Wtp   = (__bf16*)w;  w += CDIM * CDIM * 2;

  // prep
  pad_attn_frag_kernel<<<12, 256, 0, stream>>>(W_attn, b_attn, Wfrag, bpad);
  cast_wt_kernel<<<(CDIM * CDIM) / 256, 256, 0, stream>>>(W_v, Wtv);
  cast_wt_kernel<<<(CDIM * CDIM) / 256, 256, 0, stream>>>(W_proj, Wtp);

  // 0. x -> bf16 (streaming)
  cast_x_kernel<<<(NPIX * CDIM / 16) / 256, 256, 0, stream>>>(x, xb);

  // 1. logits + softmax (from xb)
  logit_softmax_kernel<<<NPIX / 64, 256, 0, stream>>>(xb, Wfrag, bpad, attn);

  // 2. v = bf16(x @ W_v + b_v)
  dim3 ggrid(NPIX / 128, CDIM / 128);
  gemm_bf16_kernel<true>
      <<<ggrid, 256, 0, stream>>>(xb, Wtv, b_v, v, NPIX, CDIM, CDIM);

  // 3. window aggregation -> y (bf16)
  aggregate_kernel<<<(NPIX * 48) / 256, 256, 0, stream>>>(v, attn, y);

  // 4. out = y @ W_proj + b_proj (fp32 out)
  gemm_bf16_kernel<false>
      <<<ggrid, 256, 0, stream>>>(y, Wtp, b_proj, out, NPIX, CDIM, CDIM);
}

// Round 7
// 135.049 us; speedup vs baseline: 1.0908x; 1.0908x over previous
//
#include <hip/hip_runtime.h>
#include <math.h>

#define NPIX 50176      // 16*56*56
#define CDIM 384
#define HEADS 6
#define NLOGIT 54       // HEADS*9
#define HH 56
#define WW 56

typedef __attribute__((ext_vector_type(8))) __bf16 bf16x8;
typedef __attribute__((ext_vector_type(4))) float f32x4;

__device__ __forceinline__ void glds16(const void* g, void* l) {
  __builtin_amdgcn_global_load_lds(
      (const __attribute__((address_space(1))) unsigned int*)g,
      (__attribute__((address_space(3))) unsigned int*)l, 16, 0, 0);
}

// ---------------------------------------------------------------------------
// W_attn [384][54] fp32 -> Wta bf16 [64][384] (row n = output col, zero rows
// 54..63); b_attn -> bpad[64].
// ---------------------------------------------------------------------------
__global__ __launch_bounds__(256) void pad_attn_kernel(
    const float* __restrict__ W, const float* __restrict__ b,
    __bf16* __restrict__ Wta, float* __restrict__ bpad) {
  const int idx = blockIdx.x * 256 + threadIdx.x;  // 64*384 = 24576
  if (idx < 64 * CDIM) {
    const int n = idx / CDIM, k = idx % CDIM;
    Wta[idx] = (__bf16)((n < NLOGIT) ? W[k * NLOGIT + n] : 0.f);
  }
  if (idx < 64) bpad[idx] = (idx < NLOGIT) ? b[idx] : 0.f;
}

// ---------------------------------------------------------------------------
// Cast + transpose weight: W fp32 [K][N] (384x384) -> Wt bf16 [N][K].
// ---------------------------------------------------------------------------
__global__ __launch_bounds__(256) void cast_wt_kernel(
    const float* __restrict__ W, __bf16* __restrict__ Wt) {
  const int idx = blockIdx.x * 256 + threadIdx.x;  // 384*384 = 147456
  const int n = idx / CDIM, k = idx % CDIM;
  Wt[n * CDIM + k] = (__bf16)W[k * CDIM + n];
}

// ---------------------------------------------------------------------------
// Cast x fp32 -> bf16, 16 elements / thread. Pure streaming.
// ---------------------------------------------------------------------------
__global__ __launch_bounds__(256) void cast_x_kernel(
    const float* __restrict__ x, __bf16* __restrict__ xb) {
  const size_t i = (size_t)blockIdx.x * 256 + threadIdx.x;  // 1204224 threads
  const float4* src = (const float4*)x + i * 4;
  const float4 f0 = src[0];
  const float4 f1 = src[1];
  const float4 f2 = src[2];
  const float4 f3 = src[3];
  bf16x8 o0, o1;
  o0[0] = (__bf16)f0.x; o0[1] = (__bf16)f0.y; o0[2] = (__bf16)f0.z; o0[3] = (__bf16)f0.w;
  o0[4] = (__bf16)f1.x; o0[5] = (__bf16)f1.y; o0[6] = (__bf16)f1.z; o0[7] = (__bf16)f1.w;
  o1[0] = (__bf16)f2.x; o1[1] = (__bf16)f2.y; o1[2] = (__bf16)f2.z; o1[3] = (__bf16)f2.w;
  o1[4] = (__bf16)f3.x; o1[5] = (__bf16)f3.y; o1[6] = (__bf16)f3.z; o1[7] = (__bf16)f3.w;
  ((bf16x8*)xb)[i * 2]     = o0;
  ((bf16x8*)xb)[i * 2 + 1] = o1;
}

// ---------------------------------------------------------------------------
// Merged dispatch: grid (NPIX/128, 4).
//   by<3 : v = bf16(xb @ Wtv^T + b_v), 128x128 tile (m97 structure).
//   by==3: logits = xb @ Wta^T + bpad (128x64), fused per-head softmax->attn.
// Logit blocks co-scheduled with MFMA-heavy gemm blocks hide their latency.
// ---------------------------------------------------------------------------
__global__ __launch_bounds__(256) void gemm_v_logit_kernel(
    const __bf16* __restrict__ xb, const __bf16* __restrict__ Wtv,
    const float* __restrict__ b_v, __bf16* __restrict__ v,
    const __bf16* __restrict__ Wta, const float* __restrict__ bpad,
    float* __restrict__ attn) {
  __shared__ char smem[34816];
  __bf16 (*As)[32] = (__bf16(*)[32])smem;            // [128][32]
  __bf16 (*Bs)[32] = (__bf16(*)[32])(smem + 8192);   // [128][32]
  float (*Ls)[68]  = (float(*)[68])smem;             // [128][68] (logit epi)

  const int tid  = threadIdx.x;
  const int wave = tid >> 6;
  const int lane = tid & 63;
  const int bm   = blockIdx.x * 128;
  const int lrow  = lane >> 2;        // 0..15
  const int lkoff = (lane & 3) * 8;   // 0,8,16,24
  const int frow  = lane & 15;
  const int fk    = (lane >> 4) * 8;

  if (blockIdx.y < 3) {
    // ---------------- v-GEMM path ----------------
    const int bn = blockIdx.y * 128;
    const int wr = (wave >> 1) * 64;
    const int wc = (wave & 1) * 64;
    f32x4 acc[4][4] = {};

    for (int k0 = 0; k0 < CDIM; k0 += 32) {
      const __bf16* ga = xb  + (size_t)(bm + wave * 32 + lrow) * CDIM + k0 + lkoff;
      const __bf16* gb = Wtv + (size_t)(bn + wave * 32 + lrow) * CDIM + k0 + lkoff;
      glds16(ga,                     &As[wave * 32][0]);
      glds16(ga + 16 * (size_t)CDIM, &As[wave * 32 + 16][0]);
      glds16(gb,                     &Bs[wave * 32][0]);
      glds16(gb + 16 * (size_t)CDIM, &Bs[wave * 32 + 16][0]);
      __syncthreads();

      bf16x8 a[4], b[4];
      #pragma unroll
      for (int mi = 0; mi < 4; ++mi)
        a[mi] = *(const bf16x8*)&As[wr + mi * 16 + frow][fk];
      #pragma unroll
      for (int ni = 0; ni < 4; ++ni)
        b[ni] = *(const bf16x8*)&Bs[wc + ni * 16 + frow][fk];
      #pragma unroll
      for (int mi = 0; mi < 4; ++mi)
        #pragma unroll
        for (int ni = 0; ni < 4; ++ni)
          acc[mi][ni] = __builtin_amdgcn_mfma_f32_16x16x32_bf16(
              a[mi], b[ni], acc[mi][ni], 0, 0, 0);
      __syncthreads();
    }

    const int orow = (lane >> 4) * 4;
    #pragma unroll
    for (int mi = 0; mi < 4; ++mi) {
      #pragma unroll
      for (int ni = 0; ni < 4; ++ni) {
        const int n = bn + wc + ni * 16 + frow;
        const float bvl = b_v[n];
        #pragma unroll
        for (int r = 0; r < 4; ++r) {
          const int m = bm + wr + mi * 16 + orow + r;
          v[(size_t)m * CDIM + n] = (__bf16)(acc[mi][ni][r] + bvl);
        }
      }
    }
  } else {
    // ---------------- logit + softmax path ----------------
    f32x4 acc[2][4] = {};

    for (int k0 = 0; k0 < CDIM; k0 += 32) {
      const __bf16* ga = xb  + (size_t)(bm + wave * 32 + lrow) * CDIM + k0 + lkoff;
      const __bf16* gb = Wta + (size_t)(wave * 16 + lrow) * CDIM + k0 + lkoff;
      glds16(ga,                     &As[wave * 32][0]);
      glds16(ga + 16 * (size_t)CDIM, &As[wave * 32 + 16][0]);
      glds16(gb,                     &Bs[wave * 16][0]);   // 64 rows total
      __syncthreads();

      bf16x8 a[2], b[4];
      #pragma unroll
      for (int mi = 0; mi < 2; ++mi)
        a[mi] = *(const bf16x8*)&As[wave * 32 + mi * 16 + frow][fk];
      #pragma unroll
      for (int ni = 0; ni < 4; ++ni)
        b[ni] = *(const bf16x8*)&Bs[ni * 16 + frow][fk];
      #pragma unroll
      for (int mi = 0; mi < 2; ++mi)
        #pragma unroll
        for (int ni = 0; ni < 4; ++ni)
          acc[mi][ni] = __builtin_amdgcn_mfma_f32_16x16x32_bf16(
              a[mi], b[ni], acc[mi][ni], 0, 0, 0);
      __syncthreads();
    }

    float bvl[4];
    #pragma unroll
    for (int ni = 0; ni < 4; ++ni) bvl[ni] = bpad[ni * 16 + frow];
    const int orow = (lane >> 4) * 4;
    #pragma unroll
    for (int mi = 0; mi < 2; ++mi)
      #pragma unroll
      for (int ni = 0; ni < 4; ++ni)
        #pragma unroll
        for (int r = 0; r < 4; ++r)
          Ls[wave * 32 + mi * 16 + orow + r][ni * 16 + frow] =
              acc[mi][ni][r] + bvl[ni];
    __syncthreads();

    // 128 pixels * 6 heads = 768 softmax tasks over 256 threads
    #pragma unroll
    for (int it = 0; it < 3; ++it) {
      const int task = it * 256 + tid;
      const int pl = task / HEADS;
      const int h  = task % HEADS;
      const float* row = &Ls[pl][h * 9];
      float m = row[0];
      #pragma unroll
      for (int w = 1; w < 9; ++w) m = fmaxf(m, row[w]);
      float e[9], s = 0.f;
      #pragma unroll
      for (int w = 0; w < 9; ++w) { e[w] = __expf(row[w] - m); s += e[w]; }
      const float inv = 1.f / s;
      float* op = &attn[(size_t)(bm + pl) * NLOGIT + h * 9];
      #pragma unroll
      for (int w = 0; w < 9; ++w) op[w] = e[w] * inv;
    }
  }
}

// ---------------------------------------------------------------------------
// bf16 MFMA GEMM (proj): Out[M][N] fp32 = A[M][K] @ Bt[N][K]^T + bias.
// ---------------------------------------------------------------------------
__global__ __launch_bounds__(256) void gemm_proj_kernel(
    const __bf16* __restrict__ A, const __bf16* __restrict__ Bt,
    const float* __restrict__ bias, float* __restrict__ Out) {
  __shared__ __bf16 As[128][32];
  __shared__ __bf16 Bs[128][32];

  const int tid  = threadIdx.x;
  const int wave = tid >> 6;
  const int lane = tid & 63;
  const int bm = blockIdx.x * 128;
  const int bn = blockIdx.y * 128;

  const int lrow  = lane >> 2;
  const int lkoff = (lane & 3) * 8;
  const int frow  = lane & 15;
  const int fk    = (lane >> 4) * 8;
  const int wr = (wave >> 1) * 64;
  const int wc = (wave & 1) * 64;

  f32x4 acc[4][4] = {};

  for (int k0 = 0; k0 < CDIM; k0 += 32) {
    const __bf16* ga = A  + (size_t)(bm + wave * 32 + lrow) * CDIM + k0 + lkoff;
    const __bf16* gb = Bt + (size_t)(bn + wave * 32 + lrow) * CDIM + k0 + lkoff;
    glds16(ga,                     &As[wave * 32][0]);
    glds16(ga + 16 * (size_t)CDIM, &As[wave * 32 + 16][0]);
    glds16(gb,                     &Bs[wave * 32][0]);
    glds16(gb + 16 * (size_t)CDIM, &Bs[wave * 32 + 16][0]);
    __syncthreads();

    bf16x8 a[4], b[4];
    #pragma unroll
    for (int mi = 0; mi < 4; ++mi)
      a[mi] = *(const bf16x8*)&As[wr + mi * 16 + frow][fk];
    #pragma unroll
    for (int ni = 0; ni < 4; ++ni)
      b[ni] = *(const bf16x8*)&Bs[wc + ni * 16 + frow][fk];
    #pragma unroll
    for (int mi = 0; mi < 4; ++mi)
      #pragma unroll
      for (int ni = 0; ni < 4; ++ni)
        acc[mi][ni] = __builtin_amdgcn_mfma_f32_16x16x32_bf16(
            a[mi], b[ni], acc[mi][ni], 0, 0, 0);
    __syncthreads();
  }

  const int orow = (lane >> 4) * 4;
  #pragma unroll
  for (int mi = 0; mi < 4; ++mi) {
    #pragma unroll
    for (int ni = 0; ni < 4; ++ni) {
      const int n = bn + wc + ni * 16 + frow;
      const float bvl = bias[n];
      #pragma unroll
      for (int r = 0; r < 4; ++r) {
        const int m = bm + wr + mi * 16 + orow + r;
        Out[(size_t)m * CDIM + n] = acc[mi][ni][r] + bvl;
      }
    }
  }
}

// ---------------------------------------------------------------------------
// Window aggregation on bf16 v: y[p,c] = sum_w attn[p,head(c),w]*v[nbr(p,w),c]
// ---------------------------------------------------------------------------
__global__ __launch_bounds__(256) void aggregate_kernel(
    const __bf16* __restrict__ v, const float* __restrict__ attn,
    __bf16* __restrict__ y) {
  const int idx = blockIdx.x * 256 + threadIdx.x;  // NPIX*48
  const int p  = idx / 48;
  const int cg = idx % 48;
  const int c  = cg * 8;
  const int b  = p / (HH * WW);
  const int ij = p % (HH * WW);
  const int i  = ij / WW;
  const int j  = ij % WW;
  const int head = c >> 6;

  const float* ap = attn + (size_t)p * NLOGIT + head * 9;
  float aw[9];
  #pragma unroll
  for (int w = 0; w < 9; ++w) aw[w] = ap[w];

  float acc[8] = {};
  #pragma unroll
  for (int ki = 0; ki < 3; ++ki) {
    const int ii = i + ki - 1;
    if (ii < 0 || ii >= HH) continue;
    #pragma unroll
    for (int kj = 0; kj < 3; ++kj) {
      const int jj = j + kj - 1;
      if (jj < 0 || jj >= WW) continue;
      const float w = aw[ki * 3 + kj];
      const bf16x8 vv =
          *(const bf16x8*)&v[((size_t)(b * HH + ii) * WW + jj) * CDIM + c];
      #pragma unroll
      for (int q = 0; q < 8; ++q) acc[q] += w * (float)vv[q];
    }
  }
  bf16x8 o;
  #pragma unroll
  for (int q = 0; q < 8; ++q) o[q] = (__bf16)acc[q];
  *(bf16x8*)&y[(size_t)p * CDIM + c] = o;
}

// ---------------------------------------------------------------------------
extern "C" void kernel_launch(void* const* d_in, const int* in_sizes, int n_in,
                              void* d_out, int out_size, void* d_ws,
                              size_t ws_size, hipStream_t stream) {
  const float* x      = (const float*)d_in[0];
  const float* W_attn = (const float*)d_in[1];
  const float* b_attn = (const float*)d_in[2];
  const float* W_v    = (const float*)d_in[3];
  const float* b_v    = (const float*)d_in[4];
  const float* W_proj = (const float*)d_in[5];
  const float* b_proj = (const float*)d_in[6];
  float* out = (float*)d_out;

  char* w = (char*)d_ws;
  __bf16* xb   = (__bf16*)w;  w += (size_t)NPIX * CDIM * 2;   // 38.5MB
  __bf16* v    = (__bf16*)w;  w += (size_t)NPIX * CDIM * 2;   // 38.5MB
  __bf16* y    = (__bf16*)w;  w += (size_t)NPIX * CDIM * 2;   // 38.5MB
  float*  attn = (float*)w;   w += (size_t)NPIX * NLOGIT * 4; // 10.8MB
  __bf16* Wta  = (__bf16*)w;  w += 64 * CDIM * 2;             // 48KB
  float*  bpad = (float*)w;   w += 64 * 4;
  __bf16* Wtv  = (__bf16*)w;  w += CDIM * CDIM * 2;
  __bf16* Wtp  = (__bf16*)w;  w += CDIM * CDIM * 2;

  // prep
  pad_attn_kernel<<<(64 * CDIM + 255) / 256, 256, 0, stream>>>(W_attn, b_attn, Wta, bpad);
  cast_wt_kernel<<<(CDIM * CDIM) / 256, 256, 0, stream>>>(W_v, Wtv);
  cast_wt_kernel<<<(CDIM * CDIM) / 256, 256, 0, stream>>>(W_proj, Wtp);

  // 0. x -> bf16 (streaming)
  cast_x_kernel<<<(NPIX * CDIM / 16) / 256, 256, 0, stream>>>(x, xb);

  // 1. merged: v-GEMM + logits/softmax
  gemm_v_logit_kernel<<<dim3(NPIX / 128, 4), 256, 0, stream>>>(
      xb, Wtv, b_v, v, Wta, bpad, attn);

  // 2. window aggregation -> y (bf16)
  aggregate_kernel<<<(NPIX * 48) / 256, 256, 0, stream>>>(v, attn, y);

  // 3. out = y @ W_proj + b_proj (fp32 out)
  gemm_proj_kernel<<<dim3(NPIX / 128, CDIM / 128), 256, 0, stream>>>(
      y, Wtp, b_proj, out);
}

// Round 8
// 119.692 us; speedup vs baseline: 1.2307x; 1.1283x over previous
//
#include <hip/hip_runtime.h>
#include <math.h>

#define NPIX 50176      // 16*56*56
#define CDIM 384
#define HEADS 6
#define NLOGIT 54       // HEADS*9
#define HH 56
#define WW 56

typedef __attribute__((ext_vector_type(8))) __bf16 bf16x8;
typedef __attribute__((ext_vector_type(4))) float f32x4;

__device__ __forceinline__ void glds16(const void* g, void* l) {
  __builtin_amdgcn_global_load_lds(
      (const __attribute__((address_space(1))) unsigned int*)g,
      (__attribute__((address_space(3))) unsigned int*)l, 16, 0, 0);
}

// ---------------------------------------------------------------------------
// One prep dispatch:
//  range 0: W_v   [K][N] -> Wtv bf16 [N][K]
//  range 1: W_proj[K][N] -> Wtp bf16 [N][K]
//  range 2: W_attn[384][54] -> Wta bf16 [64][384] (zero rows 54..63)
//  range 3: b_attn -> bpad[64]
// ---------------------------------------------------------------------------
__global__ __launch_bounds__(256) void prep_kernel(
    const float* __restrict__ W_v, const float* __restrict__ W_proj,
    const float* __restrict__ W_attn, const float* __restrict__ b_attn,
    __bf16* __restrict__ Wtv, __bf16* __restrict__ Wtp,
    __bf16* __restrict__ Wta, float* __restrict__ bpad) {
  const int idx = blockIdx.x * 256 + threadIdx.x;
  const int WSZ = CDIM * CDIM;  // 147456
  if (idx < WSZ) {
    const int n = idx / CDIM, k = idx % CDIM;
    Wtv[idx] = (__bf16)W_v[k * CDIM + n];
    Wtp[idx] = (__bf16)W_proj[k * CDIM + n];
  } else if (idx < WSZ + 64 * CDIM) {
    const int r = idx - WSZ;
    const int n = r / CDIM, k = r % CDIM;
    Wta[r] = (__bf16)((n < NLOGIT) ? W_attn[k * NLOGIT + n] : 0.f);
  } else if (idx < WSZ + 64 * CDIM + 64) {
    const int n = idx - WSZ - 64 * CDIM;
    bpad[n] = (n < NLOGIT) ? b_attn[n] : 0.f;
  }
}

// ---------------------------------------------------------------------------
// Cast x fp32 -> bf16, 16 elements / thread. Pure streaming.
// ---------------------------------------------------------------------------
__global__ __launch_bounds__(256) void cast_x_kernel(
    const float* __restrict__ x, __bf16* __restrict__ xb) {
  const size_t i = (size_t)blockIdx.x * 256 + threadIdx.x;
  const float4* src = (const float4*)x + i * 4;
  const float4 f0 = src[0];
  const float4 f1 = src[1];
  const float4 f2 = src[2];
  const float4 f3 = src[3];
  bf16x8 o0, o1;
  o0[0] = (__bf16)f0.x; o0[1] = (__bf16)f0.y; o0[2] = (__bf16)f0.z; o0[3] = (__bf16)f0.w;
  o0[4] = (__bf16)f1.x; o0[5] = (__bf16)f1.y; o0[6] = (__bf16)f1.z; o0[7] = (__bf16)f1.w;
  o1[0] = (__bf16)f2.x; o1[1] = (__bf16)f2.y; o1[2] = (__bf16)f2.z; o1[3] = (__bf16)f2.w;
  o1[4] = (__bf16)f3.x; o1[5] = (__bf16)f3.y; o1[6] = (__bf16)f3.z; o1[7] = (__bf16)f3.w;
  ((bf16x8*)xb)[i * 2]     = o0;
  ((bf16x8*)xb)[i * 2 + 1] = o1;
}

// ---------------------------------------------------------------------------
// Merged dispatch: grid (NPIX/128, 4).
//   by<3 : v = bf16(xb @ Wtv^T + b_v), 128x128 tile.
//   by==3: logits = xb @ Wta^T + bpad (128x64), fused softmax -> attn.
// ---------------------------------------------------------------------------
__global__ __launch_bounds__(256) void gemm_v_logit_kernel(
    const __bf16* __restrict__ xb, const __bf16* __restrict__ Wtv,
    const float* __restrict__ b_v, __bf16* __restrict__ v,
    const __bf16* __restrict__ Wta, const float* __restrict__ bpad,
    float* __restrict__ attn) {
  __shared__ char smem[34816];
  __bf16 (*As)[32] = (__bf16(*)[32])smem;            // [128][32]
  __bf16 (*Bs)[32] = (__bf16(*)[32])(smem + 8192);   // [128][32]
  float (*Ls)[68]  = (float(*)[68])smem;             // [128][68] (logit epi)

  const int tid  = threadIdx.x;
  const int wave = tid >> 6;
  const int lane = tid & 63;
  const int bm   = blockIdx.x * 128;
  const int lrow  = lane >> 2;
  const int lkoff = (lane & 3) * 8;
  const int frow  = lane & 15;
  const int fk    = (lane >> 4) * 8;

  if (blockIdx.y < 3) {
    const int bn = blockIdx.y * 128;
    const int wr = (wave >> 1) * 64;
    const int wc = (wave & 1) * 64;
    f32x4 acc[4][4] = {};

    for (int k0 = 0; k0 < CDIM; k0 += 32) {
      const __bf16* ga = xb  + (size_t)(bm + wave * 32 + lrow) * CDIM + k0 + lkoff;
      const __bf16* gb = Wtv + (size_t)(bn + wave * 32 + lrow) * CDIM + k0 + lkoff;
      glds16(ga,                     &As[wave * 32][0]);
      glds16(ga + 16 * (size_t)CDIM, &As[wave * 32 + 16][0]);
      glds16(gb,                     &Bs[wave * 32][0]);
      glds16(gb + 16 * (size_t)CDIM, &Bs[wave * 32 + 16][0]);
      __syncthreads();

      bf16x8 a[4], b[4];
      #pragma unroll
      for (int mi = 0; mi < 4; ++mi)
        a[mi] = *(const bf16x8*)&As[wr + mi * 16 + frow][fk];
      #pragma unroll
      for (int ni = 0; ni < 4; ++ni)
        b[ni] = *(const bf16x8*)&Bs[wc + ni * 16 + frow][fk];
      #pragma unroll
      for (int mi = 0; mi < 4; ++mi)
        #pragma unroll
        for (int ni = 0; ni < 4; ++ni)
          acc[mi][ni] = __builtin_amdgcn_mfma_f32_16x16x32_bf16(
              a[mi], b[ni], acc[mi][ni], 0, 0, 0);
      __syncthreads();
    }

    const int orow = (lane >> 4) * 4;
    #pragma unroll
    for (int mi = 0; mi < 4; ++mi) {
      #pragma unroll
      for (int ni = 0; ni < 4; ++ni) {
        const int n = bn + wc + ni * 16 + frow;
        const float bvl = b_v[n];
        #pragma unroll
        for (int r = 0; r < 4; ++r) {
          const int m = bm + wr + mi * 16 + orow + r;
          v[(size_t)m * CDIM + n] = (__bf16)(acc[mi][ni][r] + bvl);
        }
      }
    }
  } else {
    f32x4 acc[2][4] = {};

    for (int k0 = 0; k0 < CDIM; k0 += 32) {
      const __bf16* ga = xb  + (size_t)(bm + wave * 32 + lrow) * CDIM + k0 + lkoff;
      const __bf16* gb = Wta + (size_t)(wave * 16 + lrow) * CDIM + k0 + lkoff;
      glds16(ga,                     &As[wave * 32][0]);
      glds16(ga + 16 * (size_t)CDIM, &As[wave * 32 + 16][0]);
      glds16(gb,                     &Bs[wave * 16][0]);
      __syncthreads();

      bf16x8 a[2], b[4];
      #pragma unroll
      for (int mi = 0; mi < 2; ++mi)
        a[mi] = *(const bf16x8*)&As[wave * 32 + mi * 16 + frow][fk];
      #pragma unroll
      for (int ni = 0; ni < 4; ++ni)
        b[ni] = *(const bf16x8*)&Bs[ni * 16 + frow][fk];
      #pragma unroll
      for (int mi = 0; mi < 2; ++mi)
        #pragma unroll
        for (int ni = 0; ni < 4; ++ni)
          acc[mi][ni] = __builtin_amdgcn_mfma_f32_16x16x32_bf16(
              a[mi], b[ni], acc[mi][ni], 0, 0, 0);
      __syncthreads();
    }

    float bvl[4];
    #pragma unroll
    for (int ni = 0; ni < 4; ++ni) bvl[ni] = bpad[ni * 16 + frow];
    const int orow = (lane >> 4) * 4;
    #pragma unroll
    for (int mi = 0; mi < 2; ++mi)
      #pragma unroll
      for (int ni = 0; ni < 4; ++ni)
        #pragma unroll
        for (int r = 0; r < 4; ++r)
          Ls[wave * 32 + mi * 16 + orow + r][ni * 16 + frow] =
              acc[mi][ni][r] + bvl[ni];
    __syncthreads();

    #pragma unroll
    for (int it = 0; it < 3; ++it) {
      const int task = it * 256 + tid;
      const int pl = task / HEADS;
      const int h  = task % HEADS;
      const float* row = &Ls[pl][h * 9];
      float m = row[0];
      #pragma unroll
      for (int w = 1; w < 9; ++w) m = fmaxf(m, row[w]);
      float e[9], s = 0.f;
      #pragma unroll
      for (int w = 0; w < 9; ++w) { e[w] = __expf(row[w] - m); s += e[w]; }
      const float inv = 1.f / s;
      float* op = &attn[(size_t)(bm + pl) * NLOGIT + h * 9];
      #pragma unroll
      for (int w = 0; w < 9; ++w) op[w] = e[w] * inv;
    }
  }
}

// ---------------------------------------------------------------------------
// bf16 MFMA GEMM (proj): Out[M][N] fp32 = A[M][K] @ Bt[N][K]^T + bias.
// ---------------------------------------------------------------------------
__global__ __launch_bounds__(256) void gemm_proj_kernel(
    const __bf16* __restrict__ A, const __bf16* __restrict__ Bt,
    const float* __restrict__ bias, float* __restrict__ Out) {
  __shared__ __bf16 As[128][32];
  __shared__ __bf16 Bs[128][32];

  const int tid  = threadIdx.x;
  const int wave = tid >> 6;
  const int lane = tid & 63;
  const int bm = blockIdx.x * 128;
  const int bn = blockIdx.y * 128;

  const int lrow  = lane >> 2;
  const int lkoff = (lane & 3) * 8;
  const int frow  = lane & 15;
  const int fk    = (lane >> 4) * 8;
  const int wr = (wave >> 1) * 64;
  const int wc = (wave & 1) * 64;

  f32x4 acc[4][4] = {};

  for (int k0 = 0; k0 < CDIM; k0 += 32) {
    const __bf16* ga = A  + (size_t)(bm + wave * 32 + lrow) * CDIM + k0 + lkoff;
    const __bf16* gb = Bt + (size_t)(bn + wave * 32 + lrow) * CDIM + k0 + lkoff;
    glds16(ga,                     &As[wave * 32][0]);
    glds16(ga + 16 * (size_t)CDIM, &As[wave * 32 + 16][0]);
    glds16(gb,                     &Bs[wave * 32][0]);
    glds16(gb + 16 * (size_t)CDIM, &Bs[wave * 32 + 16][0]);
    __syncthreads();

    bf16x8 a[4], b[4];
    #pragma unroll
    for (int mi = 0; mi < 4; ++mi)
      a[mi] = *(const bf16x8*)&As[wr + mi * 16 + frow][fk];
    #pragma unroll
    for (int ni = 0; ni < 4; ++ni)
      b[ni] = *(const bf16x8*)&Bs[wc + ni * 16 + frow][fk];
    #pragma unroll
    for (int mi = 0; mi < 4; ++mi)
      #pragma unroll
      for (int ni = 0; ni < 4; ++ni)
        acc[mi][ni] = __builtin_amdgcn_mfma_f32_16x16x32_bf16(
            a[mi], b[ni], acc[mi][ni], 0, 0, 0);
    __syncthreads();
  }

  const int orow = (lane >> 4) * 4;
  #pragma unroll
  for (int mi = 0; mi < 4; ++mi) {
    #pragma unroll
    for (int ni = 0; ni < 4; ++ni) {
      const int n = bn + wc + ni * 16 + frow;
      const float bvl = bias[n];
      #pragma unroll
      for (int r = 0; r < 4; ++r) {
        const int m = bm + wr + mi * 16 + orow + r;
        Out[(size_t)m * CDIM + n] = acc[mi][ni][r] + bvl;
      }
    }
  }
}

// ---------------------------------------------------------------------------
// Window aggregation, 4 vertically-adjacent pixels per thread.
// Thread covers pixels (b, i0..i0+3, j), channels c..c+8. Needs v rows
// i0-1..i0+4 (6) x cols j-1..j+1 (3) = 18 chunk loads for 4 pixels
// (vs 36 in the 1-pixel version). Rows streamed to bound live registers.
// ---------------------------------------------------------------------------
__global__ __launch_bounds__(256) void aggregate_kernel(
    const __bf16* __restrict__ v, const float* __restrict__ attn,
    __bf16* __restrict__ y) {
  const int idx = blockIdx.x * 256 + threadIdx.x;  // NPIX/4 * 48 = 602112
  const int cg = idx % 48;
  const int pg = idx / 48;
  const int c  = cg * 8;
  const int b  = pg / ((HH / 4) * WW);
  const int r2 = pg % ((HH / 4) * WW);
  const int i0 = (r2 / WW) * 4;
  const int j  = r2 % WW;
  const int head = c >> 6;

  // attention weights for the 4 pixels
  const int pbase = (b * HH + i0) * WW + j;
  float aw[4][9];
  #pragma unroll
  for (int p = 0; p < 4; ++p) {
    const float* ap = attn + (size_t)(pbase + p * WW) * NLOGIT + head * 9;
    #pragma unroll
    for (int w = 0; w < 9; ++w) aw[p][w] = ap[w];
  }

  const bool j0ok = (j > 0), j2ok = (j < WW - 1);
  float acc[4][8] = {};

  #pragma unroll
  for (int li = 0; li < 6; ++li) {
    const int ii = i0 - 1 + li;
    if (ii < 0 || ii >= HH) continue;
    const __bf16* vrow = v + ((size_t)(b * HH + ii) * WW + j) * CDIM + c;
    float ch[3][8];
    #pragma unroll
    for (int kj = 0; kj < 3; ++kj) {
      const bool ok = (kj == 0) ? j0ok : (kj == 2) ? j2ok : true;
      if (ok) {
        const bf16x8 vv = *(const bf16x8*)(vrow + (kj - 1) * CDIM);
        #pragma unroll
        for (int q = 0; q < 8; ++q) ch[kj][q] = (float)vv[q];
      } else {
        #pragma unroll
        for (int q = 0; q < 8; ++q) ch[kj][q] = 0.f;
      }
    }
    // pixels p with window row index ki = li - p, ki in [0,3)
    #pragma unroll
    for (int p = 0; p < 4; ++p) {
      const int ki = li - p;
      if (ki < 0 || ki > 2) continue;
      #pragma unroll
      for (int kj = 0; kj < 3; ++kj) {
        const float w = aw[p][ki * 3 + kj];
        #pragma unroll
        for (int q = 0; q < 8; ++q) acc[p][q] += w * ch[kj][q];
      }
    }
  }

  #pragma unroll
  for (int p = 0; p < 4; ++p) {
    bf16x8 o;
    #pragma unroll
    for (int q = 0; q < 8; ++q) o[q] = (__bf16)acc[p][q];
    *(bf16x8*)&y[(size_t)(pbase + p * WW) * CDIM + c] = o;
  }
}

// ---------------------------------------------------------------------------
extern "C" void kernel_launch(void* const* d_in, const int* in_sizes, int n_in,
                              void* d_out, int out_size, void* d_ws,
                              size_t ws_size, hipStream_t stream) {
  const float* x      = (const float*)d_in[0];
  const float* W_attn = (const float*)d_in[1];
  const float* b_attn = (const float*)d_in[2];
  const float* W_v    = (const float*)d_in[3];
  const float* b_v    = (const float*)d_in[4];
  const float* W_proj = (const float*)d_in[5];
  const float* b_proj = (const float*)d_in[6];
  float* out = (float*)d_out;

  char* w = (char*)d_ws;
  __bf16* xb   = (__bf16*)w;  w += (size_t)NPIX * CDIM * 2;   // 38.5MB
  __bf16* v    = (__bf16*)w;  w += (size_t)NPIX * CDIM * 2;   // 38.5MB
  __bf16* y    = (__bf16*)w;  w += (size_t)NPIX * CDIM * 2;   // 38.5MB
  float*  attn = (float*)w;   w += (size_t)NPIX * NLOGIT * 4; // 10.8MB
  __bf16* Wta  = (__bf16*)w;  w += 64 * CDIM * 2;             // 48KB
  float*  bpad = (float*)w;   w += 64 * 4;
  __bf16* Wtv  = (__bf16*)w;  w += CDIM * CDIM * 2;
  __bf16* Wtp  = (__bf16*)w;  w += CDIM * CDIM * 2;

  // prep (one dispatch)
  const int prep_n = CDIM * CDIM + 64 * CDIM + 64;
  prep_kernel<<<(prep_n + 255) / 256, 256, 0, stream>>>(
      W_v, W_proj, W_attn, b_attn, Wtv, Wtp, Wta, bpad);

  // 0. x -> bf16 (streaming)
  cast_x_kernel<<<(NPIX * CDIM / 16) / 256, 256, 0, stream>>>(x, xb);

  // 1. merged: v-GEMM + logits/softmax
  gemm_v_logit_kernel<<<dim3(NPIX / 128, 4), 256, 0, stream>>>(
      xb, Wtv, b_v, v, Wta, bpad, attn);

  // 2. window aggregation -> y (bf16), 4 px/thread
  aggregate_kernel<<<(NPIX / 4 * 48) / 256, 256, 0, stream>>>(v, attn, y);

  // 3. out = y @ W_proj + b_proj (fp32 out)
  gemm_proj_kernel<<<dim3(NPIX / 128, CDIM / 128), 256, 0, stream>>>(
      y, Wtp, b_proj, out);
}